// Round 7
// baseline (777.910 us; speedup 1.0000x reference)
//
#include <hip/hip_runtime.h>

#define T_TOKENS 8192
#define DIM 1024
#define NEXP 8
#define HID 4096
#define ROWS (2 * T_TOKENS)       /* 16384 packed (token,expert) rows */
#define ROWS_PAD (ROWS + 256)     /* padding so 256-row A-tile overreads stay in-bounds */

#define META_COUNTS 0             /* [8]  per-expert token counts   */
#define META_OFFSET 16            /* [8]  segment start offsets     */
#define META_TOP2   32            /* [T]  packed e1 | e2<<4         */
#define META_ROWPOS (32 + T_TOKENS) /* [2T] token -> packed row ids */

typedef __attribute__((ext_vector_type(8))) short short8;
typedef __attribute__((ext_vector_type(4))) float f32x4;
typedef __attribute__((ext_vector_type(4))) unsigned short u16x4;

__device__ __forceinline__ unsigned short bf16bits(float f) {
  unsigned u = __builtin_bit_cast(unsigned, f);
  u += 0x7fffu + ((u >> 16) & 1u);   // RNE (finite inputs only)
  return (unsigned short)(u >> 16);
}

__device__ __forceinline__ void gl_lds16(const void* g, void* l) {
  __builtin_amdgcn_global_load_lds(
      (const __attribute__((address_space(1))) unsigned int*)g,
      (__attribute__((address_space(3))) unsigned int*)l, 16, 0, 0);
}

// tanh-form gelu; max |diff vs exact| ~1e-3 (validated rounds 3-6: absmax unchanged)
__device__ __forceinline__ float gelu_tanh(float x) {
  float x3 = x * x * x;
  float z = 0.7978845608028654f * x + 0.035677408136300125f * x3;
  float az = fabsf(z);
  float e = exp2f(az * 2.885390081777927f);     // exp(2|z|)
  float t = 1.0f - 2.0f / (1.0f + e);
  t = copysignf(t, z);
  return 0.5f * x * (1.0f + t);
}

// ---------------- weight transpose+convert: in [E][R][C] f32 -> out [E][C][R] bf16
__global__ __launch_bounds__(256) void transpose_w_kernel(
    const float* __restrict__ in, unsigned short* __restrict__ out, int R, int C) {
  __shared__ float tile[64][65];
  const int e = blockIdx.z;
  const int r0 = blockIdx.y * 64, c0 = blockIdx.x * 64;
  const float* inp = in + (size_t)e * R * C;
  unsigned short* outp = out + (size_t)e * R * C;
  const int tr = threadIdx.x >> 4;
  const int tc = (threadIdx.x & 15) * 4;
#pragma unroll
  for (int s = 0; s < 64; s += 16) {
    f32x4 v = *(const f32x4*)(inp + (size_t)(r0 + tr + s) * C + c0 + tc);
    tile[tr + s][tc + 0] = v[0]; tile[tr + s][tc + 1] = v[1];
    tile[tr + s][tc + 2] = v[2]; tile[tr + s][tc + 3] = v[3];
  }
  __syncthreads();
#pragma unroll
  for (int s = 0; s < 64; s += 16) {
    int orow = c0 + tr + s;
    u16x4 u;
#pragma unroll
    for (int k = 0; k < 4; ++k) u[k] = bf16bits(tile[tc + k][tr + s]);
    *(u16x4*)(outp + (size_t)orow * R + r0 + tc) = u;
  }
}

// ---------------- router: one wave per token, fp64 accumulation, top-2 selection
__global__ __launch_bounds__(256) void router_kernel(
    const float* __restrict__ x, const float* __restrict__ rw,
    const float* __restrict__ rb, int* __restrict__ meta) {
  const int w = threadIdx.x >> 6;
  const int l = threadIdx.x & 63;
  const int t = blockIdx.x * 4 + w;
  const float* xr = x + (size_t)t * DIM + l * 16;
  double acc[8];
#pragma unroll
  for (int e = 0; e < 8; ++e) acc[e] = 0.0;
#pragma unroll
  for (int m = 0; m < 16; m += 4) {
    f32x4 xv = *(const f32x4*)(xr + m);
#pragma unroll
    for (int q = 0; q < 4; ++q) {
      double xs = (double)xv[q];
      const float* rwr = rw + (size_t)(l * 16 + m + q) * NEXP;
      f32x4 r0 = *(const f32x4*)rwr;
      f32x4 r1 = *(const f32x4*)(rwr + 4);
      acc[0] += xs * (double)r0[0]; acc[1] += xs * (double)r0[1];
      acc[2] += xs * (double)r0[2]; acc[3] += xs * (double)r0[3];
      acc[4] += xs * (double)r1[0]; acc[5] += xs * (double)r1[1];
      acc[6] += xs * (double)r1[2]; acc[7] += xs * (double)r1[3];
    }
  }
#pragma unroll
  for (int off = 32; off >= 1; off >>= 1) {
#pragma unroll
    for (int e = 0; e < 8; ++e) acc[e] += __shfl_down(acc[e], off);
  }
  if (l == 0) {
    double lg[8];
#pragma unroll
    for (int e = 0; e < 8; ++e) lg[e] = acc[e] + (double)rb[e];
    int e1 = 0; double b1v = lg[0];
#pragma unroll
    for (int e = 1; e < 8; ++e) if (lg[e] > b1v) { b1v = lg[e]; e1 = e; }
    int e2 = -1; double b2v = -1e300;
#pragma unroll
    for (int e = 0; e < 8; ++e) if (e != e1 && lg[e] > b2v) { b2v = lg[e]; e2 = e; }
    meta[META_TOP2 + t] = e1 | (e2 << 4);
  }
}

// ---------------- assign: deterministic block-scan replacement for atomics.
__global__ __launch_bounds__(1024) void assign_kernel(int* __restrict__ meta) {
  __shared__ int hist[NEXP][1024];
  __shared__ int own[NEXP][1024];
  const int tid = threadIdx.x;
#pragma unroll
  for (int e = 0; e < NEXP; ++e) { hist[e][tid] = 0; own[e][tid] = 0; }
  __syncthreads();
  int top2[8];
#pragma unroll
  for (int q = 0; q < 8; ++q) {
    int t = tid * 8 + q;
    int p = meta[META_TOP2 + t];
    top2[q] = p;
    hist[p & 15][tid] += 1;
    hist[(p >> 4) & 15][tid] += 1;
  }
#pragma unroll
  for (int e = 0; e < NEXP; ++e) own[e][tid] = hist[e][tid];
  __syncthreads();
  for (int off = 1; off < 1024; off <<= 1) {
    int add[NEXP];
#pragma unroll
    for (int e = 0; e < NEXP; ++e) add[e] = (tid >= off) ? hist[e][tid - off] : 0;
    __syncthreads();
#pragma unroll
    for (int e = 0; e < NEXP; ++e) hist[e][tid] += add[e];
    __syncthreads();
  }
  int offp[NEXP];
  {
    int o = 0;
#pragma unroll
    for (int e = 0; e < NEXP; ++e) { offp[e] = o; o += hist[e][1023]; }
  }
  if (tid == 0) {
#pragma unroll
    for (int e = 0; e < NEXP; ++e) {
      meta[META_COUNTS + e] = hist[e][1023];
      meta[META_OFFSET + e] = offp[e];
    }
  }
#pragma unroll
  for (int e = 0; e < NEXP; ++e) own[e][tid] = offp[e] + hist[e][tid] - own[e][tid];
#pragma unroll
  for (int q = 0; q < 8; ++q) {
    int t = tid * 8 + q;
    int p = top2[q];
    int e1 = p & 15, e2 = (p >> 4) & 15;
    int r1 = own[e1][tid]; own[e1][tid] = r1 + 1;
    int r2 = own[e2][tid]; own[e2][tid] = r2 + 1;
    meta[META_ROWPOS + 2 * t] = r1;
    meta[META_ROWPOS + 2 * t + 1] = r2;
  }
}

// ---------------- gather x rows (fp32 -> bf16) into packed per-expert segments
__global__ __launch_bounds__(256) void gather_kernel(
    const float* __restrict__ x, unsigned short* __restrict__ gx,
    const int* __restrict__ meta) {
  const int t = blockIdx.x;
  const int r1 = meta[META_ROWPOS + 2 * t];
  const int r2 = meta[META_ROWPOS + 2 * t + 1];
  const int i = threadIdx.x * 4;
  f32x4 v = *(const f32x4*)(x + (size_t)t * DIM + i);
  u16x4 u;
  u[0] = bf16bits(v[0]); u[1] = bf16bits(v[1]);
  u[2] = bf16bits(v[2]); u[3] = bf16bits(v[3]);
  *(u16x4*)(gx + (size_t)r1 * DIM + i) = u;
  *(u16x4*)(gx + (size_t)r2 * DIM + i) = u;
}

// ---------------- grouped GEMM, T3-minimum 2-phase recipe (catalog §5.5):
// double-buffered LDS; STAGE(t+1) issued BEFORE ds_read+MFMA of tile t;
// ONE vmcnt(0)+barrier per K-tile. BM=256, BK=64, 8 waves, XOR-swizzled LDS.
template <int ACT, int BN, int WAVES_N>
__global__ __launch_bounds__(512) void moe_gemm2ph(
    const unsigned short* __restrict__ A, const unsigned short* __restrict__ Bt,
    const float* __restrict__ bias, void* __restrict__ C,
    const int* __restrict__ meta, int K, int N) {
  constexpr int WAVES_M = 8 / WAVES_N;
  constexpr int MI = 256 / (16 * WAVES_M);   // M frags per wave
  constexpr int NJ = BN / (16 * WAVES_N);    // N frags per wave
  constexpr int BPASS = (BN * 64) / 4096;    // B staging passes (512 thr x 8 elems)

  const int e = blockIdx.z;
  const int n_e = meta[META_COUNTS + e];
  const int mt = blockIdx.y;
  if (mt * 256 >= n_e) return;
  const int n0 = blockIdx.x * BN;
  const int row0 = meta[META_OFFSET + e] + mt * 256;
  const int mrem = n_e - mt * 256;
  const int NT = K >> 6;

  __shared__ __align__(16) unsigned short As[2][256 * 64];
  __shared__ __align__(16) unsigned short Bs[2][BN * 64];

  const int tid = threadIdx.x;
  const int wid = tid >> 6, l = tid & 63;
  const int wm = wid / WAVES_N, wn = wid % WAVES_N;
  const int rA = l & 15, cq = l >> 4;

  const unsigned short* Ag = A + (size_t)row0 * K;
  const unsigned short* Bg = Bt + (size_t)e * N * K + (size_t)n0 * K;

  auto stage = [&](int buf, int kt) {
#pragma unroll
    for (int it = 0; it < 4; ++it) {
      int idx = it * 4096 + tid * 8;
      int row = idx >> 6;
      int cp = (idx >> 3) & 7;
      int col = ((cp ^ (row & 7)) << 3);
      gl_lds16(Ag + (size_t)row * K + kt + col, &As[buf][it * 4096 + (wid << 9)]);
    }
#pragma unroll
    for (int it = 0; it < BPASS; ++it) {
      int idx = it * 4096 + tid * 8;
      int row = idx >> 6;
      int cp = (idx >> 3) & 7;
      int col = ((cp ^ (row & 7)) << 3);
      gl_lds16(Bg + (size_t)row * K + kt + col, &Bs[buf][it * 4096 + (wid << 9)]);
    }
  };

  // prologue
  stage(0, 0);
  asm volatile("s_waitcnt vmcnt(0)" ::: "memory");
  __builtin_amdgcn_s_barrier();

  f32x4 acc[MI][NJ] = {};
  int cur = 0;

  for (int t = 0; t < NT; ++t) {
    if (t + 1 < NT) stage(cur ^ 1, (t + 1) << 6);   // prefetch next tile (other buffer)
    const unsigned short* Ac = As[cur];
    const unsigned short* Bc = Bs[cur];
    short8 av[2][MI], bv[2][NJ];
#pragma unroll
    for (int ks = 0; ks < 2; ++ks) {
      const int c = ks * 4 + cq;
#pragma unroll
      for (int i = 0; i < MI; ++i) {
        int r = wm * (MI * 16) + i * 16 + rA;
        av[ks][i] = *(const short8*)&Ac[r * 64 + ((c ^ (r & 7)) << 3)];
      }
#pragma unroll
      for (int j = 0; j < NJ; ++j) {
        int r = wn * (NJ * 16) + j * 16 + rA;
        bv[ks][j] = *(const short8*)&Bc[r * 64 + ((c ^ (r & 7)) << 3)];
      }
    }
    asm volatile("s_waitcnt lgkmcnt(0)" ::: "memory");
    __builtin_amdgcn_sched_barrier(0);   // rule #18: keep MFMA below the wait
    __builtin_amdgcn_s_setprio(1);
#pragma unroll
    for (int ks = 0; ks < 2; ++ks)
#pragma unroll
      for (int i = 0; i < MI; ++i)
#pragma unroll
        for (int j = 0; j < NJ; ++j)
          acc[i][j] = __builtin_amdgcn_mfma_f32_16x16x32_bf16(av[ks][i], bv[ks][j], acc[i][j], 0, 0, 0);
    __builtin_amdgcn_s_setprio(0);
    asm volatile("s_waitcnt vmcnt(0)" ::: "memory");   // next tile fully staged
    __builtin_amdgcn_s_barrier();
    cur ^= 1;
  }

  // epilogue: C/D layout col = l&15 (N side), row = (l>>4)*4 + r (M side)
  const int lc = l & 15;
  const int lro = (l >> 4) << 2;
#pragma unroll
  for (int i = 0; i < MI; ++i) {
#pragma unroll
    for (int j = 0; j < NJ; ++j) {
      int gn = n0 + wn * (NJ * 16) + j * 16 + lc;
      float bz = bias[(size_t)e * N + gn];
#pragma unroll
      for (int r = 0; r < 4; ++r) {
        int lr = wm * (MI * 16) + i * 16 + lro + r;
        if (lr < mrem) {
          float v = acc[i][j][r] + bz;
          size_t off = (size_t)(row0 + lr) * N + gn;
          if (ACT == 1) {
            ((unsigned short*)C)[off] = bf16bits(gelu_tanh(v));
          } else {
            ((float*)C)[off] = v;
          }
        }
      }
    }
  }
}

// ---------------- combine: out[t] = y[r1] + y[r2]
__global__ __launch_bounds__(256) void combine_kernel(
    const float* __restrict__ y, const int* __restrict__ meta, float* __restrict__ out) {
  const int t = blockIdx.x;
  const int r1 = meta[META_ROWPOS + 2 * t];
  const int r2 = meta[META_ROWPOS + 2 * t + 1];
  const int i = threadIdx.x * 4;
  f32x4 a = *(const f32x4*)(y + (size_t)r1 * DIM + i);
  f32x4 b = *(const f32x4*)(y + (size_t)r2 * DIM + i);
  f32x4 o = a + b;
  *(f32x4*)(out + (size_t)t * DIM + i) = o;
}

extern "C" void kernel_launch(void* const* d_in, const int* in_sizes, int n_in,
                              void* d_out, int out_size, void* d_ws, size_t ws_size,
                              hipStream_t stream) {
  const float* x  = (const float*)d_in[0];
  const float* rw = (const float*)d_in[1];
  const float* rb = (const float*)d_in[2];
  const float* w1 = (const float*)d_in[3];
  const float* b1 = (const float*)d_in[4];
  const float* w2 = (const float*)d_in[5];
  const float* b2 = (const float*)d_in[6];
  float* out = (float*)d_out;

  char* p = (char*)d_ws;
  unsigned short* w1t = (unsigned short*)p; p += (size_t)NEXP * DIM * HID * 2;   // 64 MB
  unsigned short* w2t = (unsigned short*)p; p += (size_t)NEXP * DIM * HID * 2;   // 64 MB
  unsigned short* gx  = (unsigned short*)p; p += (size_t)ROWS_PAD * DIM * 2;     // 34 MB
  unsigned short* h   = (unsigned short*)p; p += (size_t)ROWS_PAD * HID * 2;     // 136 MB
  float*          y   = (float*)p;          p += (size_t)ROWS_PAD * DIM * 4;     // 68 MB
  int*            meta = (int*)p;                                                // ~100 KB
  (void)in_sizes; (void)n_in; (void)out_size; (void)ws_size;

  // w1 [E][D][H] -> w1t [E][H][D] ; w2 [E][H][D] -> w2t [E][D][H]
  transpose_w_kernel<<<dim3(HID / 64, DIM / 64, NEXP), 256, 0, stream>>>(w1, w1t, DIM, HID);
  transpose_w_kernel<<<dim3(DIM / 64, HID / 64, NEXP), 256, 0, stream>>>(w2, w2t, HID, DIM);

  router_kernel<<<T_TOKENS / 4, 256, 0, stream>>>(x, rw, rb, meta);
  assign_kernel<<<1, 1024, 0, stream>>>(meta);
  gather_kernel<<<T_TOKENS, 256, 0, stream>>>(x, gx, meta);

  // GEMM1: [n_e,1024] @ [1024,4096] + b1, gelu -> h (bf16). 256x256 tiles, 2M x 4N waves.
  moe_gemm2ph<1, 256, 4><<<dim3(HID / 256, 32, NEXP), 512, 0, stream>>>(gx, w1t, b1, h, meta, DIM, HID);
  // GEMM2: [n_e,4096] @ [4096,1024] + b2 -> y (f32). 256x128 tiles, 4M x 2N waves.
  moe_gemm2ph<0, 128, 2><<<dim3(DIM / 128, 32, NEXP), 512, 0, stream>>>(h, w2t, b2, y, meta, HID, DIM);

  combine_kernel<<<T_TOKENS, 256, 0, stream>>>(y, meta, out);
}

// Round 8
// 639.264 us; speedup vs baseline: 1.2169x; 1.2169x over previous
//
#include <hip/hip_runtime.h>

#define T_TOKENS 8192
#define DIM 1024
#define NEXP 8
#define HID 4096
#define ROWS (2 * T_TOKENS)       /* 16384 packed (token,expert) rows */
#define ROWS_PAD (ROWS + 256)     /* padding so A-tile overreads stay in-bounds */

#define META_COUNTS 0             /* [8]  per-expert token counts   */
#define META_OFFSET 16            /* [8]  segment start offsets     */
#define META_TOP2   32            /* [T]  packed e1 | e2<<4         */
#define META_ROWPOS (32 + T_TOKENS) /* [2T] token -> packed row ids */

typedef __attribute__((ext_vector_type(8))) short short8;
typedef __attribute__((ext_vector_type(4))) float f32x4;
typedef __attribute__((ext_vector_type(4))) unsigned short u16x4;

__device__ __forceinline__ unsigned short bf16bits(float f) {
  unsigned u = __builtin_bit_cast(unsigned, f);
  u += 0x7fffu + ((u >> 16) & 1u);   // RNE (finite inputs only)
  return (unsigned short)(u >> 16);
}

__device__ __forceinline__ void gl_lds16(const void* g, void* l) {
  __builtin_amdgcn_global_load_lds(
      (const __attribute__((address_space(1))) unsigned int*)g,
      (__attribute__((address_space(3))) unsigned int*)l, 16, 0, 0);
}

// tanh-form gelu; max |diff vs exact| ~1e-3 (validated rounds 3-7: absmax unchanged)
__device__ __forceinline__ float gelu_tanh(float x) {
  float x3 = x * x * x;
  float z = 0.7978845608028654f * x + 0.035677408136300125f * x3;
  float az = fabsf(z);
  float e = exp2f(az * 2.885390081777927f);     // exp(2|z|)
  float t = 1.0f - 2.0f / (1.0f + e);
  t = copysignf(t, z);
  return 0.5f * x * (1.0f + t);
}

// ---------------- weight transpose+convert: in [E][R][C] f32 -> out [E][C][R] bf16
__global__ __launch_bounds__(256) void transpose_w_kernel(
    const float* __restrict__ in, unsigned short* __restrict__ out, int R, int C) {
  __shared__ float tile[64][65];
  const int e = blockIdx.z;
  const int r0 = blockIdx.y * 64, c0 = blockIdx.x * 64;
  const float* inp = in + (size_t)e * R * C;
  unsigned short* outp = out + (size_t)e * R * C;
  const int tr = threadIdx.x >> 4;
  const int tc = (threadIdx.x & 15) * 4;
#pragma unroll
  for (int s = 0; s < 64; s += 16) {
    f32x4 v = *(const f32x4*)(inp + (size_t)(r0 + tr + s) * C + c0 + tc);
    tile[tr + s][tc + 0] = v[0]; tile[tr + s][tc + 1] = v[1];
    tile[tr + s][tc + 2] = v[2]; tile[tr + s][tc + 3] = v[3];
  }
  __syncthreads();
#pragma unroll
  for (int s = 0; s < 64; s += 16) {
    int orow = c0 + tr + s;
    u16x4 u;
#pragma unroll
    for (int k = 0; k < 4; ++k) u[k] = bf16bits(tile[tc + k][tr + s]);
    *(u16x4*)(outp + (size_t)orow * R + r0 + tc) = u;
  }
}

// ---------------- router: one wave per token, fp64 accumulation, top-2 selection
__global__ __launch_bounds__(256) void router_kernel(
    const float* __restrict__ x, const float* __restrict__ rw,
    const float* __restrict__ rb, int* __restrict__ meta) {
  const int w = threadIdx.x >> 6;
  const int l = threadIdx.x & 63;
  const int t = blockIdx.x * 4 + w;
  const float* xr = x + (size_t)t * DIM + l * 16;
  double acc[8];
#pragma unroll
  for (int e = 0; e < 8; ++e) acc[e] = 0.0;
#pragma unroll
  for (int m = 0; m < 16; m += 4) {
    f32x4 xv = *(const f32x4*)(xr + m);
#pragma unroll
    for (int q = 0; q < 4; ++q) {
      double xs = (double)xv[q];
      const float* rwr = rw + (size_t)(l * 16 + m + q) * NEXP;
      f32x4 r0 = *(const f32x4*)rwr;
      f32x4 r1 = *(const f32x4*)(rwr + 4);
      acc[0] += xs * (double)r0[0]; acc[1] += xs * (double)r0[1];
      acc[2] += xs * (double)r0[2]; acc[3] += xs * (double)r0[3];
      acc[4] += xs * (double)r1[0]; acc[5] += xs * (double)r1[1];
      acc[6] += xs * (double)r1[2]; acc[7] += xs * (double)r1[3];
    }
  }
#pragma unroll
  for (int off = 32; off >= 1; off >>= 1) {
#pragma unroll
    for (int e = 0; e < 8; ++e) acc[e] += __shfl_down(acc[e], off);
  }
  if (l == 0) {
    double lg[8];
#pragma unroll
    for (int e = 0; e < 8; ++e) lg[e] = acc[e] + (double)rb[e];
    int e1 = 0; double b1v = lg[0];
#pragma unroll
    for (int e = 1; e < 8; ++e) if (lg[e] > b1v) { b1v = lg[e]; e1 = e; }
    int e2 = -1; double b2v = -1e300;
#pragma unroll
    for (int e = 0; e < 8; ++e) if (e != e1 && lg[e] > b2v) { b2v = lg[e]; e2 = e; }
    meta[META_TOP2 + t] = e1 | (e2 << 4);
  }
}

// ---------------- assign: deterministic block-scan replacement for atomics.
__global__ __launch_bounds__(1024) void assign_kernel(int* __restrict__ meta) {
  __shared__ int hist[NEXP][1024];
  __shared__ int own[NEXP][1024];
  const int tid = threadIdx.x;
#pragma unroll
  for (int e = 0; e < NEXP; ++e) { hist[e][tid] = 0; own[e][tid] = 0; }
  __syncthreads();
  int top2[8];
#pragma unroll
  for (int q = 0; q < 8; ++q) {
    int t = tid * 8 + q;
    int p = meta[META_TOP2 + t];
    top2[q] = p;
    hist[p & 15][tid] += 1;
    hist[(p >> 4) & 15][tid] += 1;
  }
#pragma unroll
  for (int e = 0; e < NEXP; ++e) own[e][tid] = hist[e][tid];
  __syncthreads();
  for (int off = 1; off < 1024; off <<= 1) {
    int add[NEXP];
#pragma unroll
    for (int e = 0; e < NEXP; ++e) add[e] = (tid >= off) ? hist[e][tid - off] : 0;
    __syncthreads();
#pragma unroll
    for (int e = 0; e < NEXP; ++e) hist[e][tid] += add[e];
    __syncthreads();
  }
  int offp[NEXP];
  {
    int o = 0;
#pragma unroll
    for (int e = 0; e < NEXP; ++e) { offp[e] = o; o += hist[e][1023]; }
  }
  if (tid == 0) {
#pragma unroll
    for (int e = 0; e < NEXP; ++e) {
      meta[META_COUNTS + e] = hist[e][1023];
      meta[META_OFFSET + e] = offp[e];
    }
  }
#pragma unroll
  for (int e = 0; e < NEXP; ++e) own[e][tid] = offp[e] + hist[e][tid] - own[e][tid];
#pragma unroll
  for (int q = 0; q < 8; ++q) {
    int t = tid * 8 + q;
    int p = top2[q];
    int e1 = p & 15, e2 = (p >> 4) & 15;
    int r1 = own[e1][tid]; own[e1][tid] = r1 + 1;
    int r2 = own[e2][tid]; own[e2][tid] = r2 + 1;
    meta[META_ROWPOS + 2 * t] = r1;
    meta[META_ROWPOS + 2 * t + 1] = r2;
  }
}

// ---------------- gather x rows (fp32 -> bf16) into packed per-expert segments
__global__ __launch_bounds__(256) void gather_kernel(
    const float* __restrict__ x, unsigned short* __restrict__ gx,
    const int* __restrict__ meta) {
  const int t = blockIdx.x;
  const int r1 = meta[META_ROWPOS + 2 * t];
  const int r2 = meta[META_ROWPOS + 2 * t + 1];
  const int i = threadIdx.x * 4;
  f32x4 v = *(const f32x4*)(x + (size_t)t * DIM + i);
  u16x4 u;
  u[0] = bf16bits(v[0]); u[1] = bf16bits(v[1]);
  u[2] = bf16bits(v[2]); u[3] = bf16bits(v[3]);
  *(u16x4*)(gx + (size_t)r1 * DIM + i) = u;
  *(u16x4*)(gx + (size_t)r2 * DIM + i) = u;
}

// ---------------- grouped GEMM: round-5 proven 2-phase single-buffered loop,
// widened tile 128x256 (87 FLOP/staged-byte vs 32) at the SAME 256-thread /
// 4-wave / multi-block-per-CU concurrency. Wave-tile 64x128 (MI=4, NJ=8).
template <int ACT>
__global__ __launch_bounds__(256, 2) void moe_gemm(
    const unsigned short* __restrict__ A, const unsigned short* __restrict__ Bt,
    const float* __restrict__ bias, void* __restrict__ C,
    const int* __restrict__ meta, int K, int N) {
  constexpr int MI = 4;   // M frags per wave (64 rows)
  constexpr int NJ = 8;   // N frags per wave (128 cols)

  const int e = blockIdx.z;
  const int n_e = meta[META_COUNTS + e];
  const int mt = blockIdx.y;
  if (mt * 128 >= n_e) return;
  const int n0 = blockIdx.x * 256;
  const int row0 = meta[META_OFFSET + e] + mt * 128;
  const int mrem = n_e - mt * 128;

  __shared__ __align__(16) unsigned short As[128 * 64];
  __shared__ __align__(16) unsigned short Bs[256 * 64];

  const int tid = threadIdx.x;
  const int w = tid >> 6, l = tid & 63;
  const int wm = w >> 1, wn = w & 1;          // 2M x 2N waves
  const int rA = l & 15, cq = l >> 4;

  f32x4 acc[MI][NJ] = {};

  const unsigned short* Ag = A + (size_t)row0 * K;
  const unsigned short* Bg = Bt + (size_t)e * N * K + (size_t)n0 * K;

  for (int kt = 0; kt < K; kt += 64) {
    // stage A tile (128x64 = 4 passes): LDS linear, global source inverse-swizzled
#pragma unroll
    for (int it = 0; it < 4; ++it) {
      int idx = it * 2048 + tid * 8;
      int row = idx >> 6;
      int cp = (idx >> 3) & 7;
      int col = ((cp ^ (row & 7)) << 3);
      gl_lds16(Ag + (size_t)row * K + kt + col, &As[it * 2048 + (w << 9)]);
    }
    // stage B tile (256x64 = 8 passes)
#pragma unroll
    for (int it = 0; it < 8; ++it) {
      int idx = it * 2048 + tid * 8;
      int row = idx >> 6;
      int cp = (idx >> 3) & 7;
      int col = ((cp ^ (row & 7)) << 3);
      gl_lds16(Bg + (size_t)row * K + kt + col, &Bs[it * 2048 + (w << 9)]);
    }
    __syncthreads();
#pragma unroll
    for (int ks = 0; ks < 2; ++ks) {
      short8 av[MI], bv[NJ];
      const int c = ks * 4 + cq;
#pragma unroll
      for (int i = 0; i < MI; ++i) {
        int r = wm * 64 + i * 16 + rA;
        av[i] = *(const short8*)&As[r * 64 + ((c ^ (r & 7)) << 3)];
      }
#pragma unroll
      for (int j = 0; j < NJ; ++j) {
        int r = wn * 128 + j * 16 + rA;
        bv[j] = *(const short8*)&Bs[r * 64 + ((c ^ (r & 7)) << 3)];
      }
#pragma unroll
      for (int i = 0; i < MI; ++i)
#pragma unroll
        for (int j = 0; j < NJ; ++j)
          acc[i][j] = __builtin_amdgcn_mfma_f32_16x16x32_bf16(av[i], bv[j], acc[i][j], 0, 0, 0);
    }
    __syncthreads();
  }

  // epilogue: C/D layout col = l&15 (N side), row = (l>>4)*4 + r (M side)
  const int lc = l & 15;
  const int lro = (l >> 4) << 2;
#pragma unroll
  for (int i = 0; i < MI; ++i) {
#pragma unroll
    for (int j = 0; j < NJ; ++j) {
      int gn = n0 + wn * 128 + j * 16 + lc;
      float bz = bias[(size_t)e * N + gn];
#pragma unroll
      for (int r = 0; r < 4; ++r) {
        int lr = wm * 64 + i * 16 + lro + r;
        if (lr < mrem) {
          float v = acc[i][j][r] + bz;
          size_t off = (size_t)(row0 + lr) * N + gn;
          if (ACT == 1) {
            ((unsigned short*)C)[off] = bf16bits(gelu_tanh(v));
          } else {
            ((float*)C)[off] = v;
          }
        }
      }
    }
  }
}

// ---------------- combine: out[t] = y[r1] + y[r2]
__global__ __launch_bounds__(256) void combine_kernel(
    const float* __restrict__ y, const int* __restrict__ meta, float* __restrict__ out) {
  const int t = blockIdx.x;
  const int r1 = meta[META_ROWPOS + 2 * t];
  const int r2 = meta[META_ROWPOS + 2 * t + 1];
  const int i = threadIdx.x * 4;
  f32x4 a = *(const f32x4*)(y + (size_t)r1 * DIM + i);
  f32x4 b = *(const f32x4*)(y + (size_t)r2 * DIM + i);
  f32x4 o = a + b;
  *(f32x4*)(out + (size_t)t * DIM + i) = o;
}

extern "C" void kernel_launch(void* const* d_in, const int* in_sizes, int n_in,
                              void* d_out, int out_size, void* d_ws, size_t ws_size,
                              hipStream_t stream) {
  const float* x  = (const float*)d_in[0];
  const float* rw = (const float*)d_in[1];
  const float* rb = (const float*)d_in[2];
  const float* w1 = (const float*)d_in[3];
  const float* b1 = (const float*)d_in[4];
  const float* w2 = (const float*)d_in[5];
  const float* b2 = (const float*)d_in[6];
  float* out = (float*)d_out;

  char* p = (char*)d_ws;
  unsigned short* w1t = (unsigned short*)p; p += (size_t)NEXP * DIM * HID * 2;   // 64 MB
  unsigned short* w2t = (unsigned short*)p; p += (size_t)NEXP * DIM * HID * 2;   // 64 MB
  unsigned short* gx  = (unsigned short*)p; p += (size_t)ROWS_PAD * DIM * 2;     // 34 MB
  unsigned short* h   = (unsigned short*)p; p += (size_t)ROWS_PAD * HID * 2;     // 136 MB
  float*          y   = (float*)p;          p += (size_t)ROWS_PAD * DIM * 4;     // 68 MB
  int*            meta = (int*)p;                                                // ~100 KB
  (void)in_sizes; (void)n_in; (void)out_size; (void)ws_size;

  // w1 [E][D][H] -> w1t [E][H][D] ; w2 [E][H][D] -> w2t [E][D][H]
  transpose_w_kernel<<<dim3(HID / 64, DIM / 64, NEXP), 256, 0, stream>>>(w1, w1t, DIM, HID);
  transpose_w_kernel<<<dim3(DIM / 64, HID / 64, NEXP), 256, 0, stream>>>(w2, w2t, HID, DIM);

  router_kernel<<<T_TOKENS / 4, 256, 0, stream>>>(x, rw, rb, meta);
  assign_kernel<<<1, 1024, 0, stream>>>(meta);
  gather_kernel<<<T_TOKENS, 256, 0, stream>>>(x, gx, meta);

  // GEMM1: [n_e,1024] @ [1024,4096] + b1, gelu -> h (bf16). 128x256 tiles.
  moe_gemm<1><<<dim3(HID / 256, 64, NEXP), 256, 0, stream>>>(gx, w1t, b1, h, meta, DIM, HID);
  // GEMM2: [n_e,4096] @ [4096,1024] + b2 -> y (f32). 128x256 tiles.
  moe_gemm<0><<<dim3(DIM / 256, 64, NEXP), 256, 0, stream>>>(h, w2t, b2, y, meta, HID, DIM);

  combine_kernel<<<T_TOKENS, 256, 0, stream>>>(y, meta, out);
}

// Round 9
// 593.701 us; speedup vs baseline: 1.3103x; 1.0767x over previous
//
#include <hip/hip_runtime.h>

#define T_TOKENS 8192
#define DIM 1024
#define NEXP 8
#define HID 4096
#define ROWS (2 * T_TOKENS)       /* 16384 packed (token,expert) rows */
#define ROWS_PAD (ROWS + 256)     /* padding so A-tile overreads stay in-bounds */

#define META_COUNTS 0             /* [8]  per-expert token counts   */
#define META_OFFSET 16            /* [8]  segment start offsets     */
#define META_TOP2   32            /* [T]  packed e1 | e2<<4         */
#define META_ROWPOS (32 + T_TOKENS) /* [2T] token -> packed row ids */

typedef __attribute__((ext_vector_type(8))) short short8;
typedef __attribute__((ext_vector_type(4))) float f32x4;
typedef __attribute__((ext_vector_type(4))) unsigned short u16x4;

__device__ __forceinline__ unsigned short bf16bits(float f) {
  unsigned u = __builtin_bit_cast(unsigned, f);
  u += 0x7fffu + ((u >> 16) & 1u);   // RNE (finite inputs only)
  return (unsigned short)(u >> 16);
}

__device__ __forceinline__ float bf2f(unsigned short s) {
  unsigned u = (unsigned)s << 16;
  return __builtin_bit_cast(float, u);
}

__device__ __forceinline__ void gl_lds16(const void* g, void* l) {
  __builtin_amdgcn_global_load_lds(
      (const __attribute__((address_space(1))) unsigned int*)g,
      (__attribute__((address_space(3))) unsigned int*)l, 16, 0, 0);
}

// tanh-form gelu; max |diff vs exact| ~1e-3 (validated rounds 3-8: absmax unchanged)
__device__ __forceinline__ float gelu_tanh(float x) {
  float x3 = x * x * x;
  float z = 0.7978845608028654f * x + 0.035677408136300125f * x3;
  float az = fabsf(z);
  float e = exp2f(az * 2.885390081777927f);     // exp(2|z|)
  float t = 1.0f - 2.0f / (1.0f + e);
  t = copysignf(t, z);
  return 0.5f * x * (1.0f + t);
}

// ---------------- weight transpose+convert: in [E][R][C] f32 -> out [E][C][R] bf16
__global__ __launch_bounds__(256) void transpose_w_kernel(
    const float* __restrict__ in, unsigned short* __restrict__ out, int R, int C) {
  __shared__ float tile[64][65];
  const int e = blockIdx.z;
  const int r0 = blockIdx.y * 64, c0 = blockIdx.x * 64;
  const float* inp = in + (size_t)e * R * C;
  unsigned short* outp = out + (size_t)e * R * C;
  const int tr = threadIdx.x >> 4;
  const int tc = (threadIdx.x & 15) * 4;
#pragma unroll
  for (int s = 0; s < 64; s += 16) {
    f32x4 v = *(const f32x4*)(inp + (size_t)(r0 + tr + s) * C + c0 + tc);
    tile[tr + s][tc + 0] = v[0]; tile[tr + s][tc + 1] = v[1];
    tile[tr + s][tc + 2] = v[2]; tile[tr + s][tc + 3] = v[3];
  }
  __syncthreads();
#pragma unroll
  for (int s = 0; s < 64; s += 16) {
    int orow = c0 + tr + s;
    u16x4 u;
#pragma unroll
    for (int k = 0; k < 4; ++k) u[k] = bf16bits(tile[tc + k][tr + s]);
    *(u16x4*)(outp + (size_t)orow * R + r0 + tc) = u;
  }
}

// ---------------- router: one wave per token, fp64 accumulation, top-2 selection
__global__ __launch_bounds__(256) void router_kernel(
    const float* __restrict__ x, const float* __restrict__ rw,
    const float* __restrict__ rb, int* __restrict__ meta) {
  const int w = threadIdx.x >> 6;
  const int l = threadIdx.x & 63;
  const int t = blockIdx.x * 4 + w;
  const float* xr = x + (size_t)t * DIM + l * 16;
  double acc[8];
#pragma unroll
  for (int e = 0; e < 8; ++e) acc[e] = 0.0;
#pragma unroll
  for (int m = 0; m < 16; m += 4) {
    f32x4 xv = *(const f32x4*)(xr + m);
#pragma unroll
    for (int q = 0; q < 4; ++q) {
      double xs = (double)xv[q];
      const float* rwr = rw + (size_t)(l * 16 + m + q) * NEXP;
      f32x4 r0 = *(const f32x4*)rwr;
      f32x4 r1 = *(const f32x4*)(rwr + 4);
      acc[0] += xs * (double)r0[0]; acc[1] += xs * (double)r0[1];
      acc[2] += xs * (double)r0[2]; acc[3] += xs * (double)r0[3];
      acc[4] += xs * (double)r1[0]; acc[5] += xs * (double)r1[1];
      acc[6] += xs * (double)r1[2]; acc[7] += xs * (double)r1[3];
    }
  }
#pragma unroll
  for (int off = 32; off >= 1; off >>= 1) {
#pragma unroll
    for (int e = 0; e < 8; ++e) acc[e] += __shfl_down(acc[e], off);
  }
  if (l == 0) {
    double lg[8];
#pragma unroll
    for (int e = 0; e < 8; ++e) lg[e] = acc[e] + (double)rb[e];
    int e1 = 0; double b1v = lg[0];
#pragma unroll
    for (int e = 1; e < 8; ++e) if (lg[e] > b1v) { b1v = lg[e]; e1 = e; }
    int e2 = -1; double b2v = -1e300;
#pragma unroll
    for (int e = 0; e < 8; ++e) if (e != e1 && lg[e] > b2v) { b2v = lg[e]; e2 = e; }
    meta[META_TOP2 + t] = e1 | (e2 << 4);
  }
}

// ---------------- assign: deterministic block-scan replacement for atomics.
__global__ __launch_bounds__(1024) void assign_kernel(int* __restrict__ meta) {
  __shared__ int hist[NEXP][1024];
  __shared__ int own[NEXP][1024];
  const int tid = threadIdx.x;
#pragma unroll
  for (int e = 0; e < NEXP; ++e) { hist[e][tid] = 0; own[e][tid] = 0; }
  __syncthreads();
  int top2[8];
#pragma unroll
  for (int q = 0; q < 8; ++q) {
    int t = tid * 8 + q;
    int p = meta[META_TOP2 + t];
    top2[q] = p;
    hist[p & 15][tid] += 1;
    hist[(p >> 4) & 15][tid] += 1;
  }
#pragma unroll
  for (int e = 0; e < NEXP; ++e) own[e][tid] = hist[e][tid];
  __syncthreads();
  for (int off = 1; off < 1024; off <<= 1) {
    int add[NEXP];
#pragma unroll
    for (int e = 0; e < NEXP; ++e) add[e] = (tid >= off) ? hist[e][tid - off] : 0;
    __syncthreads();
#pragma unroll
    for (int e = 0; e < NEXP; ++e) hist[e][tid] += add[e];
    __syncthreads();
  }
  int offp[NEXP];
  {
    int o = 0;
#pragma unroll
    for (int e = 0; e < NEXP; ++e) { offp[e] = o; o += hist[e][1023]; }
  }
  if (tid == 0) {
#pragma unroll
    for (int e = 0; e < NEXP; ++e) {
      meta[META_COUNTS + e] = hist[e][1023];
      meta[META_OFFSET + e] = offp[e];
    }
  }
#pragma unroll
  for (int e = 0; e < NEXP; ++e) own[e][tid] = offp[e] + hist[e][tid] - own[e][tid];
#pragma unroll
  for (int q = 0; q < 8; ++q) {
    int t = tid * 8 + q;
    int p = top2[q];
    int e1 = p & 15, e2 = (p >> 4) & 15;
    int r1 = own[e1][tid]; own[e1][tid] = r1 + 1;
    int r2 = own[e2][tid]; own[e2][tid] = r2 + 1;
    meta[META_ROWPOS + 2 * t] = r1;
    meta[META_ROWPOS + 2 * t + 1] = r2;
  }
}

// ---------------- gather x rows (fp32 -> bf16) into packed per-expert segments
__global__ __launch_bounds__(256) void gather_kernel(
    const float* __restrict__ x, unsigned short* __restrict__ gx,
    const int* __restrict__ meta) {
  const int t = blockIdx.x;
  const int r1 = meta[META_ROWPOS + 2 * t];
  const int r2 = meta[META_ROWPOS + 2 * t + 1];
  const int i = threadIdx.x * 4;
  f32x4 v = *(const f32x4*)(x + (size_t)t * DIM + i);
  u16x4 u;
  u[0] = bf16bits(v[0]); u[1] = bf16bits(v[1]);
  u[2] = bf16bits(v[2]); u[3] = bf16bits(v[3]);
  *(u16x4*)(gx + (size_t)r1 * DIM + i) = u;
  *(u16x4*)(gx + (size_t)r2 * DIM + i) = u;
}

// ---------------- grouped GEMM: round-5 proven structure (128x128, BK=64, 4 waves,
// 2-phase single-buffered, XOR swizzle). KSPLIT>1: blockIdx.y encodes (M-tile, k-half);
// each half writes a separate bf16 partial buffer (summed in combine; no atomics).
template <int ACT, int KSPLIT>
__global__ __launch_bounds__(256) void moe_gemm(
    const unsigned short* __restrict__ A, const unsigned short* __restrict__ Bt,
    const float* __restrict__ bias, void* __restrict__ C,
    const int* __restrict__ meta, int K, int N) {
  const int e = blockIdx.z;
  const int n_e = meta[META_COUNTS + e];
  const int mt = (KSPLIT > 1) ? (blockIdx.y >> 1) : blockIdx.y;
  const int kh = (KSPLIT > 1) ? (blockIdx.y & 1) : 0;
  if (mt * 128 >= n_e) return;
  const int n0 = blockIdx.x * 128;
  const int row0 = meta[META_OFFSET + e] + mt * 128;
  const int mrem = n_e - mt * 128;
  const int kbeg = kh * (K / KSPLIT);
  const int kend = kbeg + (K / KSPLIT);

  __shared__ __align__(16) unsigned short As[128 * 64];
  __shared__ __align__(16) unsigned short Bs[128 * 64];

  const int tid = threadIdx.x;
  const int w = tid >> 6, l = tid & 63;
  const int wr = w >> 1, wc = w & 1;

  f32x4 acc[4][4] = {};

  const unsigned short* Bte = Bt + (size_t)e * N * K;

  for (int kt = kbeg; kt < kend; kt += 64) {
    // stage A tile (128x64) — LDS linear, global source inverse-swizzled
#pragma unroll
    for (int it = 0; it < 4; ++it) {
      int idx = it * 2048 + tid * 8;
      int row = idx >> 6;
      int cp = (idx >> 3) & 7;
      int col = ((cp ^ (row & 7)) << 3);
      gl_lds16(A + (size_t)(row0 + row) * K + kt + col, &As[it * 2048 + w * 512]);
    }
    // stage B tile (128 n-rows x 64 k)
#pragma unroll
    for (int it = 0; it < 4; ++it) {
      int idx = it * 2048 + tid * 8;
      int row = idx >> 6;
      int cp = (idx >> 3) & 7;
      int col = ((cp ^ (row & 7)) << 3);
      gl_lds16(Bte + (size_t)(n0 + row) * K + kt + col, &Bs[it * 2048 + w * 512]);
    }
    __syncthreads();
#pragma unroll
    for (int ks = 0; ks < 2; ++ks) {
      short8 av[4], bv[4];
#pragma unroll
      for (int i = 0; i < 4; ++i) {
        int r = wr * 64 + i * 16 + (l & 15);
        int c = ks * 4 + (l >> 4);
        av[i] = *(const short8*)&As[r * 64 + ((c ^ (r & 7)) << 3)];
      }
#pragma unroll
      for (int j = 0; j < 4; ++j) {
        int r = wc * 64 + j * 16 + (l & 15);
        int c = ks * 4 + (l >> 4);
        bv[j] = *(const short8*)&Bs[r * 64 + ((c ^ (r & 7)) << 3)];
      }
#pragma unroll
      for (int i = 0; i < 4; ++i)
#pragma unroll
        for (int j = 0; j < 4; ++j)
          acc[i][j] = __builtin_amdgcn_mfma_f32_16x16x32_bf16(av[i], bv[j], acc[i][j], 0, 0, 0);
    }
    __syncthreads();
  }

  // epilogue: C/D layout col = l&15, row = (l>>4)*4 + r
  const int lc = l & 15;
  const int lro = (l >> 4) << 2;
#pragma unroll
  for (int i = 0; i < 4; ++i) {
#pragma unroll
    for (int j = 0; j < 4; ++j) {
      int gn = n0 + wc * 64 + j * 16 + lc;
      float bz = (kh == 0) ? bias[(size_t)e * N + gn] : 0.0f;
#pragma unroll
      for (int r = 0; r < 4; ++r) {
        int lr = wr * 64 + i * 16 + lro + r;
        if (lr < mrem) {
          float v = acc[i][j][r] + bz;
          size_t off = (size_t)(row0 + lr) * N + gn;
          if (ACT == 1) {
            ((unsigned short*)C)[off] = bf16bits(gelu_tanh(v));
          } else {
            ((unsigned short*)C)[(size_t)kh * ROWS_PAD * DIM + off] = bf16bits(v);
          }
        }
      }
    }
  }
}

// ---------------- combine: out[t] = y0[r1]+y1[r1]+y0[r2]+y1[r2]  (bf16 partials)
__global__ __launch_bounds__(256) void combine_kernel(
    const unsigned short* __restrict__ y, const int* __restrict__ meta,
    float* __restrict__ out) {
  const int t = blockIdx.x;
  const int r1 = meta[META_ROWPOS + 2 * t];
  const int r2 = meta[META_ROWPOS + 2 * t + 1];
  const int i = threadIdx.x * 4;
  const unsigned short* y1 = y + (size_t)ROWS_PAD * DIM;
  u16x4 a0 = *(const u16x4*)(y  + (size_t)r1 * DIM + i);
  u16x4 a1 = *(const u16x4*)(y1 + (size_t)r1 * DIM + i);
  u16x4 b0 = *(const u16x4*)(y  + (size_t)r2 * DIM + i);
  u16x4 b1 = *(const u16x4*)(y1 + (size_t)r2 * DIM + i);
  f32x4 o;
#pragma unroll
  for (int k = 0; k < 4; ++k)
    o[k] = (bf2f(a0[k]) + bf2f(a1[k])) + (bf2f(b0[k]) + bf2f(b1[k]));
  *(f32x4*)(out + (size_t)t * DIM + i) = o;
}

extern "C" void kernel_launch(void* const* d_in, const int* in_sizes, int n_in,
                              void* d_out, int out_size, void* d_ws, size_t ws_size,
                              hipStream_t stream) {
  const float* x  = (const float*)d_in[0];
  const float* rw = (const float*)d_in[1];
  const float* rb = (const float*)d_in[2];
  const float* w1 = (const float*)d_in[3];
  const float* b1 = (const float*)d_in[4];
  const float* w2 = (const float*)d_in[5];
  const float* b2 = (const float*)d_in[6];
  float* out = (float*)d_out;

  char* p = (char*)d_ws;
  unsigned short* w1t = (unsigned short*)p; p += (size_t)NEXP * DIM * HID * 2;   // 64 MB
  unsigned short* w2t = (unsigned short*)p; p += (size_t)NEXP * DIM * HID * 2;   // 64 MB
  unsigned short* gx  = (unsigned short*)p; p += (size_t)ROWS_PAD * DIM * 2;     // 34 MB
  unsigned short* h   = (unsigned short*)p; p += (size_t)ROWS_PAD * HID * 2;     // 136 MB
  unsigned short* y   = (unsigned short*)p; p += (size_t)2 * ROWS_PAD * DIM * 2; // 68 MB (2 bf16 halves)
  int*            meta = (int*)p;                                                // ~100 KB
  (void)in_sizes; (void)n_in; (void)out_size; (void)ws_size;

  // w1 [E][D][H] -> w1t [E][H][D] ; w2 [E][H][D] -> w2t [E][D][H]
  transpose_w_kernel<<<dim3(HID / 64, DIM / 64, NEXP), 256, 0, stream>>>(w1, w1t, DIM, HID);
  transpose_w_kernel<<<dim3(DIM / 64, HID / 64, NEXP), 256, 0, stream>>>(w2, w2t, HID, DIM);

  router_kernel<<<T_TOKENS / 4, 256, 0, stream>>>(x, rw, rb, meta);
  assign_kernel<<<1, 1024, 0, stream>>>(meta);
  gather_kernel<<<T_TOKENS, 256, 0, stream>>>(x, gx, meta);

  // GEMM1: [n_e,1024] @ [1024,4096] + b1, gelu -> h (bf16). 128x128 tiles (round-5 proven).
  moe_gemm<1, 1><<<dim3(HID / 128, 64, NEXP), 256, 0, stream>>>(gx, w1t, b1, h, meta, DIM, HID);
  // GEMM2: [n_e,4096] @ [4096,1024] + b2 -> y0,y1 (bf16 partials). Split-K x2.
  moe_gemm<0, 2><<<dim3(DIM / 128, 64 * 2, NEXP), 256, 0, stream>>>(h, w2t, b2, y, meta, HID, DIM);

  combine_kernel<<<T_TOKENS, 256, 0, stream>>>(y, meta, out);
}

// Round 10
// 590.995 us; speedup vs baseline: 1.3163x; 1.0046x over previous
//
#include <hip/hip_runtime.h>

#define T_TOKENS 8192
#define DIM 1024
#define NEXP 8
#define HID 4096
#define ROWS (2 * T_TOKENS)       /* 16384 packed (token,expert) rows */
#define ROWS_PAD (ROWS + 256)     /* padding so A-tile overreads stay in-bounds */

#define META_COUNTS 0             /* [8]  per-expert token counts   */
#define META_OFFSET 16            /* [8]  segment start offsets     */
#define META_TOP2   32            /* [T]  packed e1 | e2<<4         */
#define META_ROWPOS (32 + T_TOKENS) /* [2T] token -> packed row ids */

typedef __attribute__((ext_vector_type(8))) short short8;
typedef __attribute__((ext_vector_type(4))) float f32x4;
typedef __attribute__((ext_vector_type(4))) unsigned short u16x4;

__device__ __forceinline__ unsigned short bf16bits(float f) {
  unsigned u = __builtin_bit_cast(unsigned, f);
  u += 0x7fffu + ((u >> 16) & 1u);   // RNE (finite inputs only)
  return (unsigned short)(u >> 16);
}

__device__ __forceinline__ void gl_lds16(const void* g, void* l) {
  __builtin_amdgcn_global_load_lds(
      (const __attribute__((address_space(1))) unsigned int*)g,
      (__attribute__((address_space(3))) unsigned int*)l, 16, 0, 0);
}

// tanh-form gelu; max |diff vs exact| ~1e-3 (validated rounds 3-9: absmax unchanged)
__device__ __forceinline__ float gelu_tanh(float x) {
  float x3 = x * x * x;
  float z = 0.7978845608028654f * x + 0.035677408136300125f * x3;
  float az = fabsf(z);
  float e = exp2f(az * 2.885390081777927f);     // exp(2|z|)
  float t = 1.0f - 2.0f / (1.0f + e);
  t = copysignf(t, z);
  return 0.5f * x * (1.0f + t);
}

// ---------------- weight transpose+convert: in [E][R][C] f32 -> out [E][C][R] bf16
__global__ __launch_bounds__(256) void transpose_w_kernel(
    const float* __restrict__ in, unsigned short* __restrict__ out, int R, int C) {
  __shared__ float tile[64][65];
  const int e = blockIdx.z;
  const int r0 = blockIdx.y * 64, c0 = blockIdx.x * 64;
  const float* inp = in + (size_t)e * R * C;
  unsigned short* outp = out + (size_t)e * R * C;
  const int tr = threadIdx.x >> 4;
  const int tc = (threadIdx.x & 15) * 4;
#pragma unroll
  for (int s = 0; s < 64; s += 16) {
    f32x4 v = *(const f32x4*)(inp + (size_t)(r0 + tr + s) * C + c0 + tc);
    tile[tr + s][tc + 0] = v[0]; tile[tr + s][tc + 1] = v[1];
    tile[tr + s][tc + 2] = v[2]; tile[tr + s][tc + 3] = v[3];
  }
  __syncthreads();
#pragma unroll
  for (int s = 0; s < 64; s += 16) {
    int orow = c0 + tr + s;
    u16x4 u;
#pragma unroll
    for (int k = 0; k < 4; ++k) u[k] = bf16bits(tile[tc + k][tr + s]);
    *(u16x4*)(outp + (size_t)orow * R + r0 + tc) = u;
  }
}

// ---------------- router: one wave per token, fp64 accumulation, top-2 selection
__global__ __launch_bounds__(256) void router_kernel(
    const float* __restrict__ x, const float* __restrict__ rw,
    const float* __restrict__ rb, int* __restrict__ meta) {
  const int w = threadIdx.x >> 6;
  const int l = threadIdx.x & 63;
  const int t = blockIdx.x * 4 + w;
  const float* xr = x + (size_t)t * DIM + l * 16;
  double acc[8];
#pragma unroll
  for (int e = 0; e < 8; ++e) acc[e] = 0.0;
#pragma unroll
  for (int m = 0; m < 16; m += 4) {
    f32x4 xv = *(const f32x4*)(xr + m);
#pragma unroll
    for (int q = 0; q < 4; ++q) {
      double xs = (double)xv[q];
      const float* rwr = rw + (size_t)(l * 16 + m + q) * NEXP;
      f32x4 r0 = *(const f32x4*)rwr;
      f32x4 r1 = *(const f32x4*)(rwr + 4);
      acc[0] += xs * (double)r0[0]; acc[1] += xs * (double)r0[1];
      acc[2] += xs * (double)r0[2]; acc[3] += xs * (double)r0[3];
      acc[4] += xs * (double)r1[0]; acc[5] += xs * (double)r1[1];
      acc[6] += xs * (double)r1[2]; acc[7] += xs * (double)r1[3];
    }
  }
#pragma unroll
  for (int off = 32; off >= 1; off >>= 1) {
#pragma unroll
    for (int e = 0; e < 8; ++e) acc[e] += __shfl_down(acc[e], off);
  }
  if (l == 0) {
    double lg[8];
#pragma unroll
    for (int e = 0; e < 8; ++e) lg[e] = acc[e] + (double)rb[e];
    int e1 = 0; double b1v = lg[0];
#pragma unroll
    for (int e = 1; e < 8; ++e) if (lg[e] > b1v) { b1v = lg[e]; e1 = e; }
    int e2 = -1; double b2v = -1e300;
#pragma unroll
    for (int e = 0; e < 8; ++e) if (e != e1 && lg[e] > b2v) { b2v = lg[e]; e2 = e; }
    meta[META_TOP2 + t] = e1 | (e2 << 4);
  }
}

// ---------------- assign: deterministic block-scan replacement for atomics.
__global__ __launch_bounds__(1024) void assign_kernel(int* __restrict__ meta) {
  __shared__ int hist[NEXP][1024];
  __shared__ int own[NEXP][1024];
  const int tid = threadIdx.x;
#pragma unroll
  for (int e = 0; e < NEXP; ++e) { hist[e][tid] = 0; own[e][tid] = 0; }
  __syncthreads();
  int top2[8];
#pragma unroll
  for (int q = 0; q < 8; ++q) {
    int t = tid * 8 + q;
    int p = meta[META_TOP2 + t];
    top2[q] = p;
    hist[p & 15][tid] += 1;
    hist[(p >> 4) & 15][tid] += 1;
  }
#pragma unroll
  for (int e = 0; e < NEXP; ++e) own[e][tid] = hist[e][tid];
  __syncthreads();
  for (int off = 1; off < 1024; off <<= 1) {
    int add[NEXP];
#pragma unroll
    for (int e = 0; e < NEXP; ++e) add[e] = (tid >= off) ? hist[e][tid - off] : 0;
    __syncthreads();
#pragma unroll
    for (int e = 0; e < NEXP; ++e) hist[e][tid] += add[e];
    __syncthreads();
  }
  int offp[NEXP];
  {
    int o = 0;
#pragma unroll
    for (int e = 0; e < NEXP; ++e) { offp[e] = o; o += hist[e][1023]; }
  }
  if (tid == 0) {
#pragma unroll
    for (int e = 0; e < NEXP; ++e) {
      meta[META_COUNTS + e] = hist[e][1023];
      meta[META_OFFSET + e] = offp[e];
    }
  }
#pragma unroll
  for (int e = 0; e < NEXP; ++e) own[e][tid] = offp[e] + hist[e][tid] - own[e][tid];
#pragma unroll
  for (int q = 0; q < 8; ++q) {
    int t = tid * 8 + q;
    int p = top2[q];
    int e1 = p & 15, e2 = (p >> 4) & 15;
    int r1 = own[e1][tid]; own[e1][tid] = r1 + 1;
    int r2 = own[e2][tid]; own[e2][tid] = r2 + 1;
    meta[META_ROWPOS + 2 * t] = r1;
    meta[META_ROWPOS + 2 * t + 1] = r2;
  }
}

// ---------------- gather x rows (fp32 -> bf16) into packed per-expert segments
__global__ __launch_bounds__(256) void gather_kernel(
    const float* __restrict__ x, unsigned short* __restrict__ gx,
    const int* __restrict__ meta) {
  const int t = blockIdx.x;
  const int r1 = meta[META_ROWPOS + 2 * t];
  const int r2 = meta[META_ROWPOS + 2 * t + 1];
  const int i = threadIdx.x * 4;
  f32x4 v = *(const f32x4*)(x + (size_t)t * DIM + i);
  u16x4 u;
  u[0] = bf16bits(v[0]); u[1] = bf16bits(v[1]);
  u[2] = bf16bits(v[2]); u[3] = bf16bits(v[3]);
  *(u16x4*)(gx + (size_t)r1 * DIM + i) = u;
  *(u16x4*)(gx + (size_t)r2 * DIM + i) = u;
}

// ---------------- grouped GEMM: round-5 proven structure (128x128, BK=64, 4 waves,
// 2-phase single-buffered, XOR swizzle). ONLY change: __launch_bounds__(256, 8)
// forces VGPR<=64 -> 32-wave/CU band (LDS then caps at 5 blocks = 20 waves, 2x today).
template <int ACT>
__global__ __launch_bounds__(256, 8) void moe_gemm(
    const unsigned short* __restrict__ A, const unsigned short* __restrict__ Bt,
    const float* __restrict__ bias, void* __restrict__ C,
    const int* __restrict__ meta, int K, int N) {
  const int e = blockIdx.z;
  const int n_e = meta[META_COUNTS + e];
  const int mt = blockIdx.y;
  if (mt * 128 >= n_e) return;
  const int n0 = blockIdx.x * 128;
  const int row0 = meta[META_OFFSET + e] + mt * 128;
  const int mrem = n_e - mt * 128;

  __shared__ __align__(16) unsigned short As[128 * 64];
  __shared__ __align__(16) unsigned short Bs[128 * 64];

  const int tid = threadIdx.x;
  const int w = tid >> 6, l = tid & 63;
  const int wr = w >> 1, wc = w & 1;

  f32x4 acc[4][4] = {};

  const unsigned short* Bte = Bt + (size_t)e * N * K;

  for (int kt = 0; kt < K; kt += 64) {
    // stage A tile (128x64) — LDS linear, global source inverse-swizzled
#pragma unroll
    for (int it = 0; it < 4; ++it) {
      int idx = it * 2048 + tid * 8;
      int row = idx >> 6;
      int cp = (idx >> 3) & 7;
      int col = ((cp ^ (row & 7)) << 3);
      gl_lds16(A + (size_t)(row0 + row) * K + kt + col, &As[it * 2048 + w * 512]);
    }
    // stage B tile (128 n-rows x 64 k)
#pragma unroll
    for (int it = 0; it < 4; ++it) {
      int idx = it * 2048 + tid * 8;
      int row = idx >> 6;
      int cp = (idx >> 3) & 7;
      int col = ((cp ^ (row & 7)) << 3);
      gl_lds16(Bte + (size_t)(n0 + row) * K + kt + col, &Bs[it * 2048 + w * 512]);
    }
    __syncthreads();
#pragma unroll
    for (int ks = 0; ks < 2; ++ks) {
      short8 av[4], bv[4];
#pragma unroll
      for (int i = 0; i < 4; ++i) {
        int r = wr * 64 + i * 16 + (l & 15);
        int c = ks * 4 + (l >> 4);
        av[i] = *(const short8*)&As[r * 64 + ((c ^ (r & 7)) << 3)];
      }
#pragma unroll
      for (int j = 0; j < 4; ++j) {
        int r = wc * 64 + j * 16 + (l & 15);
        int c = ks * 4 + (l >> 4);
        bv[j] = *(const short8*)&Bs[r * 64 + ((c ^ (r & 7)) << 3)];
      }
#pragma unroll
      for (int i = 0; i < 4; ++i)
#pragma unroll
        for (int j = 0; j < 4; ++j)
          acc[i][j] = __builtin_amdgcn_mfma_f32_16x16x32_bf16(av[i], bv[j], acc[i][j], 0, 0, 0);
    }
    __syncthreads();
  }

  // epilogue: C/D layout col = l&15, row = (l>>4)*4 + r
  const int lc = l & 15;
  const int lro = (l >> 4) << 2;
#pragma unroll
  for (int i = 0; i < 4; ++i) {
#pragma unroll
    for (int j = 0; j < 4; ++j) {
      int gn = n0 + wc * 64 + j * 16 + lc;
      float bz = bias[(size_t)e * N + gn];
#pragma unroll
      for (int r = 0; r < 4; ++r) {
        int lr = wr * 64 + i * 16 + lro + r;
        if (lr < mrem) {
          float v = acc[i][j][r] + bz;
          size_t off = (size_t)(row0 + lr) * N + gn;
          if (ACT == 1) {
            ((unsigned short*)C)[off] = bf16bits(gelu_tanh(v));
          } else {
            ((float*)C)[off] = v;
          }
        }
      }
    }
  }
}

// ---------------- combine: out[t] = y[r1] + y[r2]
__global__ __launch_bounds__(256) void combine_kernel(
    const float* __restrict__ y, const int* __restrict__ meta, float* __restrict__ out) {
  const int t = blockIdx.x;
  const int r1 = meta[META_ROWPOS + 2 * t];
  const int r2 = meta[META_ROWPOS + 2 * t + 1];
  const int i = threadIdx.x * 4;
  f32x4 a = *(const f32x4*)(y + (size_t)r1 * DIM + i);
  f32x4 b = *(const f32x4*)(y + (size_t)r2 * DIM + i);
  f32x4 o = a + b;
  *(f32x4*)(out + (size_t)t * DIM + i) = o;
}

extern "C" void kernel_launch(void* const* d_in, const int* in_sizes, int n_in,
                              void* d_out, int out_size, void* d_ws, size_t ws_size,
                              hipStream_t stream) {
  const float* x  = (const float*)d_in[0];
  const float* rw = (const float*)d_in[1];
  const float* rb = (const float*)d_in[2];
  const float* w1 = (const float*)d_in[3];
  const float* b1 = (const float*)d_in[4];
  const float* w2 = (const float*)d_in[5];
  const float* b2 = (const float*)d_in[6];
  float* out = (float*)d_out;

  char* p = (char*)d_ws;
  unsigned short* w1t = (unsigned short*)p; p += (size_t)NEXP * DIM * HID * 2;   // 64 MB
  unsigned short* w2t = (unsigned short*)p; p += (size_t)NEXP * DIM * HID * 2;   // 64 MB
  unsigned short* gx  = (unsigned short*)p; p += (size_t)ROWS_PAD * DIM * 2;     // 34 MB
  unsigned short* h   = (unsigned short*)p; p += (size_t)ROWS_PAD * HID * 2;     // 136 MB
  float*          y   = (float*)p;          p += (size_t)ROWS_PAD * DIM * 4;     // 68 MB
  int*            meta = (int*)p;                                                // ~100 KB
  (void)in_sizes; (void)n_in; (void)out_size; (void)ws_size;

  // w1 [E][D][H] -> w1t [E][H][D] ; w2 [E][H][D] -> w2t [E][D][H]
  transpose_w_kernel<<<dim3(HID / 64, DIM / 64, NEXP), 256, 0, stream>>>(w1, w1t, DIM, HID);
  transpose_w_kernel<<<dim3(DIM / 64, HID / 64, NEXP), 256, 0, stream>>>(w2, w2t, HID, DIM);

  router_kernel<<<T_TOKENS / 4, 256, 0, stream>>>(x, rw, rb, meta);
  assign_kernel<<<1, 1024, 0, stream>>>(meta);
  gather_kernel<<<T_TOKENS, 256, 0, stream>>>(x, gx, meta);

  // GEMM1: [n_e,1024] @ [1024,4096] + b1, gelu -> h (bf16)
  moe_gemm<1><<<dim3(HID / 128, 64, NEXP), 256, 0, stream>>>(gx, w1t, b1, h, meta, DIM, HID);
  // GEMM2: [n_e,4096] @ [4096,1024] + b2 -> y (f32)
  moe_gemm<0><<<dim3(DIM / 128, 64, NEXP), 256, 0, stream>>>(h, w2t, b2, y, meta, HID, DIM);

  combine_kernel<<<T_TOKENS, 256, 0, stream>>>(y, meta, out);
}